// Round 5
// baseline (303.687 us; speedup 1.0000x reference)
//
#include <hip/hip_runtime.h>
#include <hip/hip_fp16.h>
#include <math.h>

#define BB 32
#define LL 2048
#define CC 1280
#define HH 160
#define LCB 32           // pool blocks per batch (each covers 64 rows, 2 chunks)
#define LCHP 64          // partial chunks = 2 per pool block

typedef float    f4 __attribute__((ext_vector_type(4)));
typedef float    f8 __attribute__((ext_vector_type(8)));
typedef _Float16 h4 __attribute__((ext_vector_type(4)));
typedef _Float16 h8 __attribute__((ext_vector_type(8)));

// ---------------- Kernel 1a: pool partials + fp16 shadow copy of x ----------------
// grid: (LCB, B), block: 320 = 2 half-rows x 160 lanes; lane owns 8 channels.
// x read NT (read-once, don't pollute L3); xh written normal (allocate -> L3-resident).
__global__ __launch_bounds__(320) void pool_conv_k(
    const float* __restrict__ x, float* __restrict__ psum,
    float* __restrict__ pmax, _Float16* __restrict__ xh) {
  const int lcb = blockIdx.x;
  const int b   = blockIdx.y;
  const int t   = threadIdx.x;
  const int half = (t >= 160) ? 1 : 0;
  const int lane = t - half * 160;
  const int c8   = lane << 3;

  const size_t row0 = (size_t)b * LL + (size_t)lcb * 64 + half;
  const float* xp = x + row0 * CC + c8;
  _Float16*    hp = xh + row0 * CC + c8;

  f4 s0 = {0.f, 0.f, 0.f, 0.f}, s1 = s0;
  f4 m0 = {-INFINITY, -INFINITY, -INFINITY, -INFINITY}, m1 = m0;

#pragma unroll 8
  for (int l = 0; l < 32; ++l) {
    const size_t off = (size_t)l * (2 * CC);
    f4 v0 = __builtin_nontemporal_load(reinterpret_cast<const f4*>(xp + off));
    f4 v1 = __builtin_nontemporal_load(reinterpret_cast<const f4*>(xp + off + 4));
    s0 += v0; s1 += v1;
    m0.x = fmaxf(m0.x, v0.x); m0.y = fmaxf(m0.y, v0.y);
    m0.z = fmaxf(m0.z, v0.z); m0.w = fmaxf(m0.w, v0.w);
    m1.x = fmaxf(m1.x, v1.x); m1.y = fmaxf(m1.y, v1.y);
    m1.z = fmaxf(m1.z, v1.z); m1.w = fmaxf(m1.w, v1.w);
    f8 w = __builtin_shufflevector(v0, v1, 0, 1, 2, 3, 4, 5, 6, 7);
    *reinterpret_cast<h8*>(hp + off) = __builtin_convertvector(w, h8);
  }
  const int chunk = (lcb << 1) | half;
  const size_t o = ((size_t)chunk * BB + b) * CC + c8;
  *reinterpret_cast<f4*>(psum + o)     = s0;
  *reinterpret_cast<f4*>(psum + o + 4) = s1;
  *reinterpret_cast<f4*>(pmax + o)     = m0;
  *reinterpret_cast<f4*>(pmax + o + 4) = m1;
}

// ---------------- Kernel 1b: fallback (no fp16 shadow) ----------------
__global__ __launch_bounds__(320) void pool_k(
    const float* __restrict__ x, float* __restrict__ psum,
    float* __restrict__ pmax) {
  const int lcb = blockIdx.x;
  const int b   = blockIdx.y;
  const int t   = threadIdx.x;
  const int half = (t >= 160) ? 1 : 0;
  const int lane = t - half * 160;
  const int c8   = lane << 3;

  const size_t row0 = (size_t)b * LL + (size_t)lcb * 64 + half;
  const float* xp = x + row0 * CC + c8;

  f4 s0 = {0.f, 0.f, 0.f, 0.f}, s1 = s0;
  f4 m0 = {-INFINITY, -INFINITY, -INFINITY, -INFINITY}, m1 = m0;
#pragma unroll 8
  for (int l = 0; l < 32; ++l) {
    const size_t off = (size_t)l * (2 * CC);
    f4 v0 = *reinterpret_cast<const f4*>(xp + off);
    f4 v1 = *reinterpret_cast<const f4*>(xp + off + 4);
    s0 += v0; s1 += v1;
    m0.x = fmaxf(m0.x, v0.x); m0.y = fmaxf(m0.y, v0.y);
    m0.z = fmaxf(m0.z, v0.z); m0.w = fmaxf(m0.w, v0.w);
    m1.x = fmaxf(m1.x, v1.x); m1.y = fmaxf(m1.y, v1.y);
    m1.z = fmaxf(m1.z, v1.z); m1.w = fmaxf(m1.w, v1.w);
  }
  const int chunk = (lcb << 1) | half;
  const size_t o = ((size_t)chunk * BB + b) * CC + c8;
  *reinterpret_cast<f4*>(psum + o)     = s0;
  *reinterpret_cast<f4*>(psum + o + 4) = s1;
  *reinterpret_cast<f4*>(pmax + o)     = m0;
  *reinterpret_cast<f4*>(pmax + o + 4) = m1;
}

// ---------------- Kernel 2: finish pools + layer 1 fused ----------------
// grid: 64 blocks (r<32: gap row b=r; r>=32: gmp row b=r-32), block: 320
__global__ __launch_bounds__(320) void finish_l1_k(
    const float* __restrict__ psum, const float* __restrict__ pmax,
    const float* __restrict__ w1, const float* __restrict__ b1,
    float* __restrict__ hout) {
  __shared__ float v[CC];
  __shared__ float part[HH];

  const int r = blockIdx.x;
  const int t = threadIdx.x;
  const int b = r & (BB - 1);
  const bool ismax = (r >= BB);

  for (int c = t; c < CC; c += 320) {
    if (!ismax) {
      float s = 0.f;
      for (int lc = 0; lc < LCHP; ++lc)
        s += psum[((size_t)lc * BB + b) * CC + c];
      v[c] = s * (1.0f / (float)LL);
    } else {
      float m = -INFINITY;
      for (int lc = 0; lc < LCHP; ++lc)
        m = fmaxf(m, pmax[((size_t)lc * BB + b) * CC + c]);
      v[c] = m;
    }
  }
  __syncthreads();

  const int h  = (t < HH) ? t : t - HH;
  const int k0 = (t < HH) ? 0 : CC / 2;
  float acc = 0.f;
#pragma unroll 8
  for (int k = 0; k < CC / 2; ++k)
    acc = fmaf(v[k0 + k], w1[(size_t)(k0 + k) * HH + h], acc);
  if (t >= HH) part[h] = acc;
  __syncthreads();
  if (t < HH) {
    float a = acc + part[t] + b1[t];
    hout[(size_t)r * HH + t] = fmaxf(a, 0.f);
  }
}

// ---------------- Kernel 3: layer 2 + sigmoid -> attn[B][C] ----------------
__global__ __launch_bounds__(256) void layer2_k(
    const float* __restrict__ hout, const float* __restrict__ w2,
    const float* __restrict__ b2, float* __restrict__ attn) {
  __shared__ float u[HH];
  const int b  = blockIdx.y;
  const int ct = blockIdx.x;
  const int t  = threadIdx.x;

  if (t < HH)
    u[t] = hout[(size_t)b * HH + t] + hout[(size_t)(b + BB) * HH + t];
  __syncthreads();

  const int c = ct * 256 + t;
  float acc = 2.0f * b2[c];
#pragma unroll 8
  for (int h = 0; h < HH; ++h)
    acc = fmaf(u[h], w2[(size_t)h * CC + c], acc);
  attn[(size_t)b * CC + c] = 1.0f / (1.0f + expf(-acc));
}

// ---------------- Kernel 4a: out = fp32(x_h) * attn ----------------
// grid: (B*L/16) reverse order, block: 320 = 2 half-rows x 160 lanes x 8 ch.
// attn held in regs (16 rows share b); NT stores keep xh resident in L3.
__global__ __launch_bounds__(320) void apply_h_k(
    const _Float16* __restrict__ xh, const float* __restrict__ attn,
    float* __restrict__ out) {
  const size_t blk = (size_t)(gridDim.x - 1 - blockIdx.x);
  const size_t r0  = blk * 16;        // 16 | 2048 -> same b
  const int b = (int)(r0 >> 11);      // L = 2048
  const int t = threadIdx.x;
  const int half = (t >= 160) ? 1 : 0;
  const int lane = t - half * 160;
  const int c8 = lane << 3;

  const float* ap = attn + (size_t)b * CC + c8;
  const f4 a0 = *reinterpret_cast<const f4*>(ap);
  const f4 a1 = *reinterpret_cast<const f4*>(ap + 4);

  const size_t base = (r0 + half) * CC + c8;
  const _Float16* hp = xh + base;
  float* op = out + base;

#pragma unroll
  for (int i = 0; i < 8; ++i) {
    const size_t off = (size_t)i * (2 * CC);
    h8 hv = *reinterpret_cast<const h8*>(hp + off);
    f8 v = __builtin_convertvector(hv, f8);
    f4 v0 = __builtin_shufflevector(v, v, 0, 1, 2, 3);
    f4 v1 = __builtin_shufflevector(v, v, 4, 5, 6, 7);
    f4 o0 = v0 * a0;
    f4 o1 = v1 * a1;
    __builtin_nontemporal_store(o0, reinterpret_cast<f4*>(op + off));
    __builtin_nontemporal_store(o1, reinterpret_cast<f4*>(op + off + 4));
  }
}

// ---------------- Kernel 4b: fallback, read fp32 x ----------------
__global__ __launch_bounds__(320) void apply_f_k(
    const float* __restrict__ x, const float* __restrict__ attn,
    float* __restrict__ out) {
  const size_t r0 = (size_t)(gridDim.x - 1 - blockIdx.x) * 8;
  const int b = (int)(r0 >> 11);
  const int c4 = threadIdx.x << 2;

  const f4 a = *reinterpret_cast<const f4*>(attn + (size_t)b * CC + c4);
  const float* xp = x + r0 * CC + c4;
  float* op = out + r0 * CC + c4;

#pragma unroll
  for (int i = 0; i < 8; ++i) {
    f4 v = *reinterpret_cast<const f4*>(xp + (size_t)i * CC);
    f4 o = v * a;
    __builtin_nontemporal_store(o, reinterpret_cast<f4*>(op + (size_t)i * CC));
  }
}

extern "C" void kernel_launch(void* const* d_in, const int* in_sizes, int n_in,
                              void* d_out, int out_size, void* d_ws, size_t ws_size,
                              hipStream_t stream) {
  const float* x  = (const float*)d_in[0];
  const float* w1 = (const float*)d_in[1];
  const float* b1 = (const float*)d_in[2];
  const float* w2 = (const float*)d_in[3];
  const float* b2 = (const float*)d_in[4];
  float* out = (float*)d_out;

  // ws layout: xh[B*L*C] fp16, then psum[LCHP][B][C], pmax[LCHP][B][C], hout[64][H], attn[B][C]
  const size_t n_x = (size_t)BB * LL * CC;
  const size_t f32_elems = (size_t)LCHP * BB * CC * 2 + (size_t)2 * BB * HH + (size_t)BB * CC;
  const bool use_h = ws_size >= n_x * sizeof(_Float16) + f32_elems * sizeof(float);

  _Float16* xh = (_Float16*)d_ws;
  float* fbase = use_h ? (float*)((char*)d_ws + n_x * sizeof(_Float16)) : (float*)d_ws;
  float* psum = fbase;
  float* pmax = psum + (size_t)LCHP * BB * CC;
  float* hout = pmax + (size_t)LCHP * BB * CC;
  float* attn = hout + (size_t)2 * BB * HH;

  if (use_h)
    pool_conv_k<<<dim3(LCB, BB), 320, 0, stream>>>(x, psum, pmax, xh);
  else
    pool_k<<<dim3(LCB, BB), 320, 0, stream>>>(x, psum, pmax);

  finish_l1_k<<<2 * BB, 320, 0, stream>>>(psum, pmax, w1, b1, hout);
  layer2_k<<<dim3(CC / 256, BB), 256, 0, stream>>>(hout, w2, b2, attn);

  if (use_h)
    apply_h_k<<<BB * LL / 16, 320, 0, stream>>>(xh, attn, out);
  else
    apply_f_k<<<BB * LL / 8, 320, 0, stream>>>(x, attn, out);
}

// Round 6
// 223.475 us; speedup vs baseline: 1.3589x; 1.3589x over previous
//
#include <hip/hip_runtime.h>
#include <hip/hip_fp16.h>
#include <math.h>

#define BB 32
#define LL 2048
#define CC 1280
#define HH 160
#define LCH 32            // pool blocks per batch; each covers 32 row-pairs (64 rows)
#define LCHP 32           // partial chunks (1 per pool block)
#define PPB 16            // row-pairs per apply block

typedef float    f4 __attribute__((ext_vector_type(4)));
typedef float    f8 __attribute__((ext_vector_type(8)));
typedef _Float16 h8 __attribute__((ext_vector_type(8)));

// xh layout: [B][L/2][C/4][8] halves — pair-tile of 2*CC halves; within a tile,
// lane t owns halves [8t, 8t+8) = {row0 c4..c4+3, row1 c4..c4+3}. All accesses
// to xh are 16B/lane unit-stride.

// ---------------- Kernel 1a: pool partials + fp16 row-pair shadow of x ----------------
// grid: (LCH, B), block 320; lane owns channels [4t, 4t+4).
// x read NT (read-once, don't allocate L3); xh written normal (L3-resident).
__global__ __launch_bounds__(320) void pool_conv_k(
    const float* __restrict__ x, float* __restrict__ psum,
    float* __restrict__ pmax, _Float16* __restrict__ xh) {
  const int lcb = blockIdx.x;
  const int b   = blockIdx.y;
  const int t   = threadIdx.x;
  const int c4  = t << 2;

  const int lp0 = lcb * 32;  // first row-pair of this block
  const float* xp = x + ((size_t)b * LL + (size_t)lp0 * 2) * CC + c4;
  _Float16*    hp = xh + ((size_t)b * (LL / 2) + lp0) * (2 * CC) + (size_t)t * 8;

  f4 s = {0.f, 0.f, 0.f, 0.f};
  f4 m = {-INFINITY, -INFINITY, -INFINITY, -INFINITY};

#pragma unroll 8
  for (int p = 0; p < 32; ++p) {
    const float* row = xp + (size_t)p * (2 * CC);
    f4 v0 = __builtin_nontemporal_load(reinterpret_cast<const f4*>(row));
    f4 v1 = __builtin_nontemporal_load(reinterpret_cast<const f4*>(row + CC));
    s += v0;
    s += v1;
    m.x = fmaxf(m.x, fmaxf(v0.x, v1.x));
    m.y = fmaxf(m.y, fmaxf(v0.y, v1.y));
    m.z = fmaxf(m.z, fmaxf(v0.z, v1.z));
    m.w = fmaxf(m.w, fmaxf(v0.w, v1.w));
    f8 w = __builtin_shufflevector(v0, v1, 0, 1, 2, 3, 4, 5, 6, 7);
    *reinterpret_cast<h8*>(hp + (size_t)p * (2 * CC)) = __builtin_convertvector(w, h8);
  }
  const size_t o = ((size_t)lcb * BB + b) * CC + c4;
  *reinterpret_cast<f4*>(psum + o) = s;
  *reinterpret_cast<f4*>(pmax + o) = m;
}

// ---------------- Kernel 1b: fallback (no fp16 shadow) ----------------
__global__ __launch_bounds__(320) void pool_k(
    const float* __restrict__ x, float* __restrict__ psum,
    float* __restrict__ pmax) {
  const int lcb = blockIdx.x;
  const int b   = blockIdx.y;
  const int c4  = threadIdx.x << 2;

  const float* xp = x + ((size_t)b * LL + (size_t)lcb * 64) * CC + c4;
  f4 s = {0.f, 0.f, 0.f, 0.f};
  f4 m = {-INFINITY, -INFINITY, -INFINITY, -INFINITY};
#pragma unroll 8
  for (int l = 0; l < 64; ++l) {
    f4 v = *reinterpret_cast<const f4*>(xp + (size_t)l * CC);
    s += v;
    m.x = fmaxf(m.x, v.x); m.y = fmaxf(m.y, v.y);
    m.z = fmaxf(m.z, v.z); m.w = fmaxf(m.w, v.w);
  }
  const size_t o = ((size_t)lcb * BB + b) * CC + c4;
  *reinterpret_cast<f4*>(psum + o) = s;
  *reinterpret_cast<f4*>(pmax + o) = m;
}

// ---------------- Kernel 2: finish pools + layer 1 fused ----------------
// grid: 64 blocks (r<32: gap row b=r; r>=32: gmp row b=r-32), block 320
__global__ __launch_bounds__(320) void finish_l1_k(
    const float* __restrict__ psum, const float* __restrict__ pmax,
    const float* __restrict__ w1, const float* __restrict__ b1,
    float* __restrict__ hout) {
  __shared__ float v[CC];
  __shared__ float part[HH];

  const int r = blockIdx.x;
  const int t = threadIdx.x;
  const int b = r & (BB - 1);
  const bool ismax = (r >= BB);

  for (int c = t; c < CC; c += 320) {
    if (!ismax) {
      float s = 0.f;
      for (int lc = 0; lc < LCHP; ++lc)
        s += psum[((size_t)lc * BB + b) * CC + c];
      v[c] = s * (1.0f / (float)LL);
    } else {
      float m = -INFINITY;
      for (int lc = 0; lc < LCHP; ++lc)
        m = fmaxf(m, pmax[((size_t)lc * BB + b) * CC + c]);
      v[c] = m;
    }
  }
  __syncthreads();

  const int h  = (t < HH) ? t : t - HH;
  const int k0 = (t < HH) ? 0 : CC / 2;
  float acc = 0.f;
#pragma unroll 8
  for (int k = 0; k < CC / 2; ++k)
    acc = fmaf(v[k0 + k], w1[(size_t)(k0 + k) * HH + h], acc);
  if (t >= HH) part[h] = acc;
  __syncthreads();
  if (t < HH) {
    float a = acc + part[t] + b1[t];
    hout[(size_t)r * HH + t] = fmaxf(a, 0.f);
  }
}

// ---------------- Kernel 3: layer 2 + sigmoid -> attn[B][C] ----------------
__global__ __launch_bounds__(256) void layer2_k(
    const float* __restrict__ hout, const float* __restrict__ w2,
    const float* __restrict__ b2, float* __restrict__ attn) {
  __shared__ float u[HH];
  const int b  = blockIdx.y;
  const int ct = blockIdx.x;
  const int t  = threadIdx.x;

  if (t < HH)
    u[t] = hout[(size_t)b * HH + t] + hout[(size_t)(b + BB) * HH + t];
  __syncthreads();

  const int c = ct * 256 + t;
  float acc = 2.0f * b2[c];
#pragma unroll 8
  for (int h = 0; h < HH; ++h)
    acc = fmaf(u[h], w2[(size_t)h * CC + c], acc);
  attn[(size_t)b * CC + c] = 1.0f / (1.0f + expf(-acc));
}

// ---------------- Kernel 4a: out = fp32(x_h) * attn ----------------
// grid: (B*L/2/PPB = 2048) reverse order, block 320; lane owns channels [4t,4t+4).
// Per pair: one 16B h8 load -> two 16B NT f4 stores. attn in regs per block.
__global__ __launch_bounds__(320) void apply_h_k(
    const _Float16* __restrict__ xh, const float* __restrict__ attn,
    float* __restrict__ out) {
  const int t  = threadIdx.x;
  const int c4 = t << 2;
  const size_t pg0 = (size_t)(gridDim.x - 1 - blockIdx.x) * PPB;  // first row-pair
  const int b = (int)(pg0 >> 10);            // L/2 = 1024 pairs per batch; PPB | 1024
  const int lp = (int)(pg0 & 1023);

  const f4 a = *reinterpret_cast<const f4*>(attn + (size_t)b * CC + c4);
  const _Float16* hp = xh + pg0 * (2 * CC) + (size_t)t * 8;
  float* op = out + ((size_t)b * LL + (size_t)lp * 2) * CC + c4;

#pragma unroll
  for (int i = 0; i < PPB; ++i) {
    h8 hv = *reinterpret_cast<const h8*>(hp + (size_t)i * (2 * CC));
    f8 v = __builtin_convertvector(hv, f8);
    f4 v0 = __builtin_shufflevector(v, v, 0, 1, 2, 3);
    f4 v1 = __builtin_shufflevector(v, v, 4, 5, 6, 7);
    f4 o0 = v0 * a;
    f4 o1 = v1 * a;
    float* orow = op + (size_t)i * (2 * CC);
    __builtin_nontemporal_store(o0, reinterpret_cast<f4*>(orow));
    __builtin_nontemporal_store(o1, reinterpret_cast<f4*>(orow + CC));
  }
}

// ---------------- Kernel 4b: fallback, read fp32 x ----------------
__global__ __launch_bounds__(320) void apply_f_k(
    const float* __restrict__ x, const float* __restrict__ attn,
    float* __restrict__ out) {
  const size_t r0 = (size_t)(gridDim.x - 1 - blockIdx.x) * 8;
  const int b = (int)(r0 >> 11);
  const int c4 = threadIdx.x << 2;

  const f4 a = *reinterpret_cast<const f4*>(attn + (size_t)b * CC + c4);
  const float* xp = x + r0 * CC + c4;
  float* op = out + r0 * CC + c4;

#pragma unroll
  for (int i = 0; i < 8; ++i) {
    f4 v = *reinterpret_cast<const f4*>(xp + (size_t)i * CC);
    f4 o = v * a;
    __builtin_nontemporal_store(o, reinterpret_cast<f4*>(op + (size_t)i * CC));
  }
}

extern "C" void kernel_launch(void* const* d_in, const int* in_sizes, int n_in,
                              void* d_out, int out_size, void* d_ws, size_t ws_size,
                              hipStream_t stream) {
  const float* x  = (const float*)d_in[0];
  const float* w1 = (const float*)d_in[1];
  const float* b1 = (const float*)d_in[2];
  const float* w2 = (const float*)d_in[3];
  const float* b2 = (const float*)d_in[4];
  float* out = (float*)d_out;

  // ws layout: xh[B*L*C] fp16 (pair-interleaved), then psum[LCHP][B][C],
  // pmax[LCHP][B][C], hout[64][H], attn[B][C]
  const size_t n_x = (size_t)BB * LL * CC;
  const size_t f32_elems = (size_t)LCHP * BB * CC * 2 + (size_t)2 * BB * HH + (size_t)BB * CC;
  const bool use_h = ws_size >= n_x * sizeof(_Float16) + f32_elems * sizeof(float);

  _Float16* xh = (_Float16*)d_ws;
  float* fbase = use_h ? (float*)((char*)d_ws + n_x * sizeof(_Float16)) : (float*)d_ws;
  float* psum = fbase;
  float* pmax = psum + (size_t)LCHP * BB * CC;
  float* hout = pmax + (size_t)LCHP * BB * CC;
  float* attn = hout + (size_t)2 * BB * HH;

  if (use_h)
    pool_conv_k<<<dim3(LCH, BB), 320, 0, stream>>>(x, psum, pmax, xh);
  else
    pool_k<<<dim3(LCH, BB), 320, 0, stream>>>(x, psum, pmax);

  finish_l1_k<<<2 * BB, 320, 0, stream>>>(psum, pmax, w1, b1, hout);
  layer2_k<<<dim3(CC / 256, BB), 256, 0, stream>>>(hout, w2, b2, attn);

  if (use_h)
    apply_h_k<<<BB * LL / 2 / PPB, 320, 0, stream>>>(xh, attn, out);
  else
    apply_f_k<<<BB * LL / 8, 320, 0, stream>>>(x, attn, out);
}